// Round 7
// baseline (448.191 us; speedup 1.0000x reference)
//
#include <hip/hip_runtime.h>

typedef unsigned short u16;
typedef unsigned int   u32;

using bf16x8 = __attribute__((ext_vector_type(8))) __bf16;
using f32x4  = __attribute__((ext_vector_type(4))) float;

__device__ __forceinline__ float bf2f(u16 h){ return __uint_as_float(((u32)h) << 16); }
__device__ __forceinline__ u16 f2bf(float f){
    u32 u = __float_as_uint(f);
    u32 r = u + 0x7FFFu + ((u >> 16) & 1u);   // round-to-nearest-even
    return (u16)(r >> 16);
}

// async global->LDS, 16B per lane; LDS dest = wave-uniform base + lane*16.
__device__ __forceinline__ void async16(const void* g, void* l){
    __builtin_amdgcn_global_load_lds(
        (const __attribute__((address_space(1))) unsigned int*)g,
        (__attribute__((address_space(3))) unsigned int*)l, 16, 0, 0);
}
__device__ __forceinline__ bf16x8 cvt8(uint4 v){
    union { uint4 u; bf16x8 b; } c; c.u = v; return c.b;
}

// ---------------------------------------------------------------------------
// Block 0: dtype probe. flags[0]=1 if floats bf16; flags[1]=mask dtype
// 0=u8,1=i32,2=bf16,3=f32.
// Block 1: label grouping: slot_of_node[n] = label*128+rank (<128) else
// 384+ovf_rank; node_of_slot inverse (-1 = empty); ovf_flag = #overflow.
// ---------------------------------------------------------------------------
__global__ void probe_and_perm(const void* x, const void* masks, int* flags,
                               const int* labels, int* slot_of_node,
                               int* node_of_slot, int* ovf_flag)
{
    if (blockIdx.x == 0){
        int l = threadIdx.x;
        if (l < 64){
            const u16* hx = (const u16*)x;
            int e0 = (hx[l] >> 7) & 0xFF;
            int e1 = (hx[l + 64] >> 7) & 0xFF;
            unsigned long long b0 = __ballot(e0 >= 100 && e0 <= 140);
            unsigned long long b1 = __ballot(e1 >= 100 && e1 <= 140);
            int cnt = __popcll(b0) + __popcll(b1);
            const u32* w  = (const u32*)masks;
            const u16* hm = (const u16*)masks;
            u32 v = w[l];
            unsigned long long i32bad = __ballot(v > 1u);
            unsigned long long f32bad = __ballot(v != 0u && v != 0x3F800000u);
            u16 h0 = hm[l], h1 = hm[l + 64];
            unsigned long long bfbad =
                __ballot((h0 != 0 && h0 != 0x3F80) || (h1 != 0 && h1 != 0x3F80));
            if (l == 0){
                flags[0] = (cnt >= 100) ? 1 : 0;
                int md = 0;
                if (!i32bad) md = 1; else if (!f32bad) md = 3; else if (!bfbad) md = 2;
                flags[1] = md;
            }
        }
        return;
    }
    __shared__ int lab[300];
    __shared__ unsigned char sp[300];
    int t = threadIdx.x;                      // 320 threads
    for (int idx = t; idx < 512; idx += 320) node_of_slot[idx] = -1;
    if (t < 300) lab[t] = labels[t];
    __syncthreads();
    int r = 0;
    if (t < 300){
        int k = lab[t];
        for (int j = 0; j < t; j++) r += (lab[j] == k);
        sp[t] = (r >= 128) ? 1 : 0;
    }
    __syncthreads();
    if (t < 300){
        int slot;
        if (!sp[t]) slot = lab[t] * 128 + r;
        else {
            int so = 0;
            for (int j = 0; j < t; j++) so += sp[j];
            slot = 384 + so;
        }
        slot_of_node[t] = slot;
        node_of_slot[slot] = t;
    }
    if (t == 0){
        int tot = 0;
        for (int j = 0; j < 300; j++) tot += sp[j];
        *ovf_flag = tot;
    }
}

// ---------------------------------------------------------------------------
// One flat-grid prep kernel: feat transpose (x -> [p][c]), B1T (W1 -> [m][c]),
// W2T (W2 -> [k][r][q]), and bias packing. All bf16-convert, zero-pad j >= J.
// ---------------------------------------------------------------------------
__global__ void prep_combo(const void* x,
    const void* w10, const void* w11, const void* w12,
    const void* w20, const void* w21, const void* w22,
    const void* bb10, const void* bb11, const void* bb12,
    const void* bb20, const void* bb21, const void* bb22,
    u16* feat, u16* B1T, u16* W2T, float* b1f, float* b2f, const int* flags)
{
    __shared__ float tile[32][33];
    const int id = blockIdx.x;
    const bool isbf = (flags[0] != 0);
    const int tid = threadIdx.x;
    const int tx = tid & 31, ty = tid >> 5;

    const void* src; u16* d; int I, J, ldd, i0, j0;
    if (id < 10016){
        int fx = id % 1252, fy = id / 1252;
        src = x; d = feat; I = 256; J = 40000; ldd = 256;
        j0 = fx * 32; i0 = fy * 32;
    } else if (id < 10016 + 768){
        int idx = id - 10016;
        int z = idx / 256, r2 = idx % 256;
        src = (z == 0) ? w10 : (z == 1) ? w11 : w12;
        d = B1T + (size_t)z * 1024 * 256;
        I = 256; J = 1024; ldd = 256;
        j0 = (r2 % 32) * 32; i0 = (r2 / 32) * 32;
    } else if (id < 10016 + 768 + 3072){
        int idx = id - 10016 - 768;
        int z = idx / 1024, r2 = idx % 1024;
        src = (z == 0) ? w20 : (z == 1) ? w21 : w22;
        d = W2T + (size_t)z * 1024 * 1024;
        I = 1024; J = 1024; ldd = 1024;
        j0 = (r2 % 32) * 32; i0 = (r2 / 32) * 32;
    } else {
        int idx = (id - 10016 - 768 - 3072) * 256 + tid;
        if (idx < 3072){
            int k = idx >> 10, r2 = idx & 1023;
            const void* p1 = (k == 0) ? bb10 : (k == 1) ? bb11 : bb12;
            const void* p2 = (k == 0) ? bb20 : (k == 1) ? bb21 : bb22;
            b1f[idx] = isbf ? bf2f(((const u16*)p1)[r2]) : ((const float*)p1)[r2];
            b2f[idx] = isbf ? bf2f(((const u16*)p2)[r2]) : ((const float*)p2)[r2];
        }
        return;
    }
    #pragma unroll
    for (int s = 0; s < 32; s += 8){
        int i = i0 + ty + s, j = j0 + tx;
        float v = 0.f;
        if (j < J){
            size_t ix = (size_t)i * J + j;
            v = isbf ? bf2f(((const u16*)src)[ix]) : ((const float*)src)[ix];
        }
        tile[ty + s][tx] = v;
    }
    __syncthreads();
    #pragma unroll
    for (int s = 0; s < 32; s += 8){
        int j = j0 + ty + s, i = i0 + tx;
        d[(size_t)j * ldd + i] = f2bf(tile[tx][ty + s]);
    }
}

// ---------------------------------------------------------------------------
// masks [P][NN] -> mfT[slot][p] bf16 {0,1} (rows permuted), fused popcount.
// ---------------------------------------------------------------------------
__global__ void trans_mask_count(const void* src, u16* dst,
                                 const int* slot_of_node, float* counts,
                                 const int* flags)
{
    constexpr int NN_ = 300, P_ = 40000, LDP = 40064;
    __shared__ u16 tile[128][33];    // [p_in][n_in]
    __shared__ int slt[32];
    const int p0 = blockIdx.x * 128, n0 = blockIdx.y * 32;
    const int tid = threadIdx.x;
    const int md = flags[1];
    if (tid < 32) slt[tid] = (n0 + tid < NN_) ? slot_of_node[n0 + tid] : -1;

    if (md == 0){
        const unsigned char* s8 = (const unsigned char*)src;
        const int tx = tid & 7, ty = tid >> 3;
        #pragma unroll
        for (int rep = 0; rep < 4; rep++){
            const int p = p0 + rep * 32 + ty;
            const int nb = n0 + tx * 4;
            u32 w = 0;
            if (p < P_){
                if (nb + 3 < NN_)
                    w = *(const u32*)(s8 + (size_t)p * NN_ + nb);
                else {
                    for (int b = 0; b < 4; b++)
                        if (nb + b < NN_)
                            w |= (u32)s8[(size_t)p * NN_ + nb + b] << (8 * b);
                }
            }
            #pragma unroll
            for (int b = 0; b < 4; b++)
                tile[rep * 32 + ty][tx * 4 + b] =
                    ((w >> (8 * b)) & 0xFFu) ? (u16)0x3F80 : (u16)0;
        }
    } else {
        #pragma unroll
        for (int it = 0; it < 16; it++){
            const int e = tid + it * 256;
            const int n_in = e & 31, p_in = e >> 5;
            const int p = p0 + p_in, n = n0 + n_in;
            u16 v = 0;
            if (p < P_ && n < NN_){
                size_t idx = (size_t)p * NN_ + n;
                bool on;
                if (md == 1)      on = ((const int*)src)[idx] != 0;
                else if (md == 2) on = ((const u16*)src)[idx] != 0;
                else              on = ((const float*)src)[idx] != 0.f;
                v = on ? (u16)0x3F80 : (u16)0;
            }
            tile[p_in][n_in] = v;
        }
    }
    __syncthreads();

    #pragma unroll
    for (int half = 0; half < 2; half++){
        const int row = tid >> 3;
        const int pos = (tid & 7) + half * 8;
        const int slot = slt[row];
        if (slot >= 0){
            union { u16 h[8]; uint4 v; } tmp;
            #pragma unroll
            for (int j = 0; j < 8; j++) tmp.h[j] = tile[pos * 8 + j][row];
            *reinterpret_cast<uint4*>(&dst[(size_t)slot * LDP + p0 + pos * 8]) = tmp.v;
        }
    }
    if (tid < 32){
        const int slot = slt[tid];
        if (slot >= 0){
            int c = 0;
            for (int p = 0; p < 128; p++) c += (tile[p][tid] != 0);
            if (c > 0) atomicAdd(&counts[slot], (float)c);
        }
    }
}

// ---------------------------------------------------------------------------
// FUSED L1 + mask-sum v7: barrier-free K-loop + triad XCD swizzle + depth-2
// register prefetch.
//  - B1T m-panel (64 KB) in LDS once per block; feat B-frags global->VGPR
//    with distance-2 pipelining (bgv[2]); mask even-frags at kt=6, odd at
//    kt=7; next p-tile's kt0/kt1 issued under stage-2 half-B.
//  - Triad swizzle: the 3 blocks of (xcd, y) share ONE feat p-chunk and
//    (mostly) one mask slice -> per-XCD L2 working set ~3.4 MB < 4 MB.
// MAP 0: grouped slots, sums=[3*128][1024], grid 504.
// MAP 1: overflow slots, sums=[128][3072]; early-out when no overflow.
// ---------------------------------------------------------------------------
template<int MAP>
__global__ __launch_bounds__(256, 2)
void fused_l1_mask(const u16* __restrict__ B1T, const u16* __restrict__ feat,
                   const u16* __restrict__ mfT, const float* __restrict__ b1f,
                   float* __restrict__ sums, const int* __restrict__ skipf)
{
    if constexpr (MAP == 1){ if (*skipf == 0) return; }
    constexpr int PPAD = 40064;
    __shared__ __align__(16) u16 As[32768];   // [kt][128][32]  64 KB
    __shared__ __align__(16) u16 Hs[8192];    // [lc][128][32]  16 KB

    int bx, ts, te;
    if constexpr (MAP == 0){
        // id = (y*3+s3)*8 + xcd ; bx = xcd*3 + s3. Triad (xcd,y) = 3 blocks
        // with the same p-chunk on one XCD (round-robin id%8 dispatch).
        const int id = blockIdx.x;            // 0..503
        const int x8 = id & 7, g = id >> 3;   // g 0..62
        const int y = g / 3, s3 = g % 3;
        bx = x8 * 3 + s3;
        ts = y * 15; te = ts + 15; if (te > 313) te = 313;
    } else {
        bx = blockIdx.x;
        ts = blockIdx.y * 40; te = ts + 40; if (te > 313) te = 313;
        if (ts >= te) return;
    }
    const int m0 = bx * 128;
    const int srow = (MAP == 0) ? ((bx >> 3) * 128) : 384;

    const int tid = threadIdx.x;
    const int wave = tid >> 6, lane = tid & 63;
    const int wr = wave >> 1, wc = wave & 1;
    const int t = lane & 15, q = lane >> 4;

    // stage B1T panel into As once: per wave per kt, 2 chunks of 16 rows x 64B
    const int cr = lane >> 2, cp = lane & 3;
    const int ca = wave * 2, cb = wave * 2 + 1;
    {
        const u16* gA0 = B1T + (size_t)(m0 + ca * 16 + cr) * 256 + cp * 8;
        const u16* gA1 = B1T + (size_t)(m0 + cb * 16 + cr) * 256 + cp * 8;
        #pragma unroll
        for (int kt = 0; kt < 8; kt++){
            async16(gA0 + kt * 32, &As[kt * 4096 + ca * 512]);
            async16(gA1 + kt * 32, &As[kt * 4096 + cb * 512]);
        }
    }

    float bv[4][4];
    #pragma unroll
    for (int mi = 0; mi < 4; mi++)
        #pragma unroll
        for (int i = 0; i < 4; i++)
            bv[mi][i] = b1f[m0 + wr*64 + mi*16 + q*4 + i];

    const u16* mrow = mfT + (size_t)(srow + wr*64 + t) * PPAD;
    const u16* gF = feat + (size_t)(wc*64 + t) * 256 + q * 8;  // + p*256 + kt*32

    f32x4 acc2[4][4];
    #pragma unroll
    for (int a = 0; a < 4; a++)
        #pragma unroll
        for (int b = 0; b < 4; b++)
            #pragma unroll
            for (int e = 0; e < 4; e++) acc2[a][b][e] = 0.f;

    // prefetch feat frags for (ts, kt=0) and (ts, kt=1)
    uint4 bgv[2][4];
    #pragma unroll
    for (int ni = 0; ni < 4; ni++){
        bgv[0][ni] = *reinterpret_cast<const uint4*>(
            gF + (size_t)(ts * 128 + ni * 16) * 256);
        bgv[1][ni] = *reinterpret_cast<const uint4*>(
            gF + (size_t)(ts * 128 + ni * 16) * 256 + 32);
    }

    __syncthreads();   // As resident + bgv arrived

    for (int pt = ts; pt < te; ++pt){
        const int p0 = pt * 128;

        f32x4 acc1[4][4];
        #pragma unroll
        for (int a = 0; a < 4; a++)
            #pragma unroll
            for (int b = 0; b < 4; b++)
                #pragma unroll
                for (int e = 0; e < 4; e++) acc1[a][b][e] = 0.f;

        uint4 ma[2][4], mb[2][4];

        // ---- stage-1 K-loop: NO barriers, distance-2 feat pipeline ----
        #pragma unroll
        for (int kt = 0; kt < 8; ++kt){
            const int cur = kt & 1;
            bf16x8 af[4];
            #pragma unroll
            for (int mi = 0; mi < 4; mi++)
                af[mi] = *reinterpret_cast<const bf16x8*>(
                    &As[kt*4096 + (wr*64 + mi*16 + t)*32 + q*8]);
            uint4 nxt[4];
            if (kt < 6){
                #pragma unroll
                for (int ni = 0; ni < 4; ni++)
                    nxt[ni] = *reinterpret_cast<const uint4*>(
                        gF + (size_t)(p0 + ni*16) * 256 + (kt + 2) * 32);
            } else if (kt == 6){
                #pragma unroll
                for (int mi = 0; mi < 4; mi++){   // mask frags, even pcs {0,2}
                    ma[0][mi] = *reinterpret_cast<const uint4*>(
                        mrow + (size_t)(mi*16)*PPAD + p0 + 0*32 + q*8);
                    ma[1][mi] = *reinterpret_cast<const uint4*>(
                        mrow + (size_t)(mi*16)*PPAD + p0 + 2*32 + q*8);
                }
            } else {
                #pragma unroll
                for (int mi = 0; mi < 4; mi++){   // mask frags, odd pcs {1,3}
                    mb[0][mi] = *reinterpret_cast<const uint4*>(
                        mrow + (size_t)(mi*16)*PPAD + p0 + 1*32 + q*8);
                    mb[1][mi] = *reinterpret_cast<const uint4*>(
                        mrow + (size_t)(mi*16)*PPAD + p0 + 3*32 + q*8);
                }
            }
            #pragma unroll
            for (int mi = 0; mi < 4; mi++)
                #pragma unroll
                for (int ni = 0; ni < 4; ni++)
                    acc1[mi][ni] = __builtin_amdgcn_mfma_f32_16x16x32_bf16(
                        af[mi], cvt8(bgv[cur][ni]), acc1[mi][ni], 0, 0, 0);
            if (kt < 6){
                #pragma unroll
                for (int ni = 0; ni < 4; ni++) bgv[cur][ni] = nxt[ni];
            }
        }

        // ---- half A: even pc chunks {0 (wc0), 2 (wc1)}, lc = wc ----
        #pragma unroll
        for (int mi = 0; mi < 4; mi++){
            #pragma unroll
            for (int i = 0; i < 4; i++){
                const int m_l = wr*64 + mi*16 + q*4 + i;
                const float bb = bv[mi][i];
                #pragma unroll
                for (int ni = 0; ni < 2; ni++){
                    const int pin = ni*16 + t;
                    float v = acc1[mi][ni][i] + bb;
                    v = (v > 0.f) ? v : 0.f;
                    const int cg = (pin >> 3) ^ q;
                    Hs[wc*4096 + m_l*32 + cg*8 + (pin & 7)] = f2bf(v);
                }
            }
        }
        __syncthreads();
        #pragma unroll
        for (int lc = 0; lc < 2; lc++){
            bf16x8 hb[4];
            #pragma unroll
            for (int ni = 0; ni < 4; ni++)
                hb[ni] = *reinterpret_cast<const bf16x8*>(
                    &Hs[lc*4096 + (wc*64 + ni*16 + t)*32 + ((q ^ (t >> 2)) * 8)]);
            #pragma unroll
            for (int mi = 0; mi < 4; mi++)
                #pragma unroll
                for (int ni = 0; ni < 4; ni++)
                    acc2[mi][ni] = __builtin_amdgcn_mfma_f32_16x16x32_bf16(
                        cvt8(ma[lc][mi]), hb[ni], acc2[mi][ni], 0, 0, 0);
        }
        __syncthreads();

        // ---- half B: odd pc chunks {1 (wc0), 3 (wc1)}, lc = wc ----
        #pragma unroll
        for (int mi = 0; mi < 4; mi++){
            #pragma unroll
            for (int i = 0; i < 4; i++){
                const int m_l = wr*64 + mi*16 + q*4 + i;
                const float bb = bv[mi][i];
                #pragma unroll
                for (int ni = 2; ni < 4; ni++){
                    const int pin = (ni & 1)*16 + t;
                    float v = acc1[mi][ni][i] + bb;
                    v = (v > 0.f) ? v : 0.f;
                    const int cg = (pin >> 3) ^ q;
                    Hs[wc*4096 + m_l*32 + cg*8 + (pin & 7)] = f2bf(v);
                }
            }
        }
        // prefetch next p-tile feat kt0/kt1 (consumed after next barrier + body)
        if (pt + 1 < te){
            #pragma unroll
            for (int ni = 0; ni < 4; ni++){
                bgv[0][ni] = *reinterpret_cast<const uint4*>(
                    gF + (size_t)((pt + 1) * 128 + ni * 16) * 256);
                bgv[1][ni] = *reinterpret_cast<const uint4*>(
                    gF + (size_t)((pt + 1) * 128 + ni * 16) * 256 + 32);
            }
        }
        __syncthreads();
        #pragma unroll
        for (int lc = 0; lc < 2; lc++){
            bf16x8 hb[4];
            #pragma unroll
            for (int ni = 0; ni < 4; ni++)
                hb[ni] = *reinterpret_cast<const bf16x8*>(
                    &Hs[lc*4096 + (wc*64 + ni*16 + t)*32 + ((q ^ (t >> 2)) * 8)]);
            #pragma unroll
            for (int mi = 0; mi < 4; mi++)
                #pragma unroll
                for (int ni = 0; ni < 4; ni++)
                    acc2[mi][ni] = __builtin_amdgcn_mfma_f32_16x16x32_bf16(
                        cvt8(mb[lc][mi]), hb[ni], acc2[mi][ni], 0, 0, 0);
        }
        __syncthreads();   // protect Hs before next p-tile's writes
    }

    // dump accumulators (rows = slots, cols = m)
    #pragma unroll
    for (int mi = 0; mi < 4; mi++){
        #pragma unroll
        for (int i = 0; i < 4; i++){
            const int slot_l = wr*64 + mi*16 + q*4 + i;
            #pragma unroll
            for (int ni = 0; ni < 4; ni++){
                const int m_l = wc*64 + ni*16 + t;
                const float v = acc2[mi][ni][i];
                if constexpr (MAP == 0)
                    atomicAdd(sums + (size_t)((bx>>3)*128 + slot_l)*1024
                                   + (bx&7)*128 + m_l, v);
                else
                    atomicAdd(sums + (size_t)slot_l*3072 + bx*128 + m_l, v);
            }
        }
    }
}

// ---------------------------------------------------------------------------
// L2 GEMM, fully fused: A = sums (fp32) scaled by 1/count and converted to
// bf16 during LDS staging (means never materialized); B = W2T; epilogue adds
// bias and scatters straight to d_out via node_of_slot (select_out fused).
// blockIdx.z: 0..2 normal branches, 3..5 overflow branches (flag-gated).
// ---------------------------------------------------------------------------
__global__ __launch_bounds__(256)
void l2_gemm(const float* __restrict__ sums3, const float* __restrict__ sumsOvf,
             const float* __restrict__ counts, const u16* __restrict__ W2T,
             const float* __restrict__ b2f, const int* __restrict__ node_of_slot,
             const int* __restrict__ labels, const int* __restrict__ ovfflag,
             void* __restrict__ dout, const int* __restrict__ flags)
{
    const int z = blockIdx.z;
    const int k = (z >= 3) ? z - 3 : z;
    if (z >= 3 && *ovfflag == 0) return;
    const int n0 = blockIdx.x * 128;

    const float* Arow; int astride, slotbase;
    if (z < 3){ Arow = sums3 + (size_t)z * 128 * 1024; astride = 1024; slotbase = z * 128; }
    else      { Arow = sumsOvf + (size_t)k * 1024;     astride = 3072; slotbase = 384; }

    __shared__ __align__(16) u16 As[4096];
    __shared__ __align__(16) u16 Bs[4096];
    __shared__ float invc[128];

    const int tid  = threadIdx.x;
    const int wave = tid >> 6, lane = tid & 63;
    const int wr = wave >> 1, wc = wave & 1;
    const int t = lane & 15, q = lane >> 4;

    if (tid < 128){
        float c = counts[slotbase + tid];
        invc[tid] = (c > 0.f) ? 1.f / c : 0.f;
    }

    const u16* Bsrc = W2T + (size_t)k * 1024 * 1024;
    const int cr = lane >> 2, cp = lane & 3;
    const int ca = wave * 2, cb = wave * 2 + 1;
    const u16* gB0 = Bsrc + (size_t)(n0 + ca * 16 + cr) * 1024 + cp * 8;
    const u16* gB1 = Bsrc + (size_t)(n0 + cb * 16 + cr) * 1024 + cp * 8;

    f32x4 acc[4][4];
    #pragma unroll
    for (int a = 0; a < 4; a++)
        #pragma unroll
        for (int b = 0; b < 4; b++)
            #pragma unroll
            for (int e = 0; e < 4; e++) acc[a][b][e] = 0.f;

    for (int kt = 0; kt < 32; ++kt){
        __syncthreads();
        // A staging: fp32 -> scale -> bf16
        #pragma unroll
        for (int rep = 0; rep < 2; rep++){
            int idx = tid + rep * 256;
            int row = idx >> 2, quarter = idx & 3;
            const float4* src = reinterpret_cast<const float4*>(
                Arow + (size_t)row * astride + kt * 32 + quarter * 8);
            float4 v0 = src[0], v1 = src[1];
            float s = invc[row];
            union { u16 h[8]; uint4 v; } pk;
            pk.h[0] = f2bf(v0.x * s); pk.h[1] = f2bf(v0.y * s);
            pk.h[2] = f2bf(v0.z * s); pk.h[3] = f2bf(v0.w * s);
            pk.h[4] = f2bf(v1.x * s); pk.h[5] = f2bf(v1.y * s);
            pk.h[6] = f2bf(v1.z * s); pk.h[7] = f2bf(v1.w * s);
            *reinterpret_cast<uint4*>(&As[row * 32 + quarter * 8]) = pk.v;
        }
        // B staging
        async16(gB0 + kt * 32, Bs + ca * 512);
        async16(gB1 + kt * 32, Bs + cb * 512);
        __syncthreads();
        bf16x8 af[4], bg[4];
        #pragma unroll
        for (int mi = 0; mi < 4; mi++)
            af[mi] = *reinterpret_cast<const bf16x8*>(
                &As[(wr*64 + mi*16 + t)*32 + q*8]);
        #pragma unroll
        for (int ni = 0; ni < 4; ni++)
            bg[ni] = *reinterpret_cast<const bf16x8*>(
                &Bs[(wc*64 + ni*16 + t)*32 + q*8]);
        #pragma unroll
        for (int mi = 0; mi < 4; mi++)
            #pragma unroll
            for (int ni = 0; ni < 4; ni++)
                acc[mi][ni] = __builtin_amdgcn_mfma_f32_16x16x32_bf16(
                    af[mi], bg[ni], acc[mi][ni], 0, 0, 0);
    }

    const bool outbf = (flags[0] != 0);
    #pragma unroll
    for (int mi = 0; mi < 4; mi++){
        #pragma unroll
        for (int i = 0; i < 4; i++){
            int m_l = wr*64 + mi*16 + q*4 + i;
            int node = node_of_slot[slotbase + m_l];
            bool ok = (node >= 0) && (z < 3 || labels[node] == k);
            if (!ok) continue;
            #pragma unroll
            for (int ni = 0; ni < 4; ni++){
                int n = n0 + wc*64 + ni*16 + t;
                float v = acc[mi][ni][i] + b2f[k * 1024 + n];
                size_t oi = (size_t)node * 1024 + n;
                if (outbf) ((u16*)dout)[oi] = f2bf(v);
                else       ((float*)dout)[oi] = v;
            }
        }
    }
}

// ---------------------------------------------------------------------------
extern "C" void kernel_launch(void* const* d_in, const int* in_sizes, int n_in,
                              void* d_out, int out_size, void* d_ws, size_t ws_size,
                              hipStream_t stream)
{
    constexpr int C = 256, R = 1024;
    constexpr int PPAD = 40064;          // 313 * 128
    constexpr int M1 = 3 * R;            // 3072 L1 rows (branch-major)
    constexpr int SLOTS = 512;           // 3*128 grouped + 128 overflow

    const void* x      = d_in[0];
    const void* masks  = d_in[1];
    const int*  labels = (const int*)d_in[2];
    (void)in_sizes; (void)n_in; (void)out_size; (void)ws_size;

    char* ws = (char*)d_ws;
    size_t off = 0;
    auto alloc = [&](size_t b)->size_t {
        size_t o = off; off += (b + 255) & ~(size_t)255; return o;
    };

    int*   flags   = (int*)  (ws + alloc(256));
    int*   slotmap = (int*)  (ws + alloc(384 * 4));
    int*   nodemap = (int*)  (ws + alloc(512 * 4));
    int*   ovfflag = (int*)  (ws + alloc(256));
    u16*   feat    = (u16*)  (ws + alloc((size_t)PPAD * C * 2));    // [p][c]
    u16*   B1T     = (u16*)  (ws + alloc((size_t)M1 * C * 2));      // [m][c]
    float* b1f     = (float*)(ws + alloc((size_t)M1 * 4));
    float* b2f     = (float*)(ws + alloc((size_t)M1 * 4));
    u16*   mfT     = (u16*)  (ws + alloc((size_t)SLOTS * PPAD * 2));// [slot][p]
    // contiguous zero region: sums3 | sumsOvf | counts
    float* sums3   = (float*)(ws + alloc((size_t)384 * 1024 * 4));
    float* sumsOvf = (float*)(ws + alloc((size_t)128 * M1 * 4));
    float* counts  = (float*)(ws + alloc((size_t)SLOTS * 4));
    u16*   W2T     = (u16*)  (ws + alloc((size_t)3 * R * R * 2));

    probe_and_perm<<<2, 320, 0, stream>>>(x, masks, flags, labels,
                                          slotmap, nodemap, ovfflag);
    hipMemsetAsync(mfT, 0, (size_t)SLOTS * PPAD * 2, stream);
    hipMemsetAsync(sums3, 0,
        (size_t)384 * 1024 * 4 + (size_t)128 * M1 * 4 + (size_t)SLOTS * 4, stream);

    prep_combo<<<10016 + 768 + 3072 + 12, 256, 0, stream>>>(
        x, d_in[3], d_in[7], d_in[11],           // W1
        d_in[5], d_in[9], d_in[13],              // W2
        d_in[4], d_in[8], d_in[12],              // b1
        d_in[6], d_in[10], d_in[14],             // b2
        feat, B1T, W2T, b1f, b2f, flags);

    trans_mask_count<<<dim3(PPAD / 128, 384 / 32), 256, 0, stream>>>(
        masks, mfT, slotmap, counts, flags);

    // fused L1 + mask-sum: 504 blocks = 63 triads x 8 XCDs, 2 blocks/CU
    fused_l1_mask<0><<<504, 256, 0, stream>>>(
        B1T, feat, mfT, b1f, sums3, nullptr);
    // overflow path (skipped unless some label has > 128 nodes)
    fused_l1_mask<1><<<dim3(24, 8), 256, 0, stream>>>(
        B1T, feat, mfT, b1f, sumsOvf, ovfflag);

    // L2 + means + output gather, one launch
    l2_gemm<<<dim3(8, 1, 6), 256, 0, stream>>>(
        sums3, sumsOvf, counts, W2T, b2f, nodemap, labels, ovfflag,
        d_out, flags);
}

// Round 8
// 378.619 us; speedup vs baseline: 1.1837x; 1.1837x over previous
//
#include <hip/hip_runtime.h>

typedef unsigned short u16;
typedef unsigned int   u32;

using bf16x8 = __attribute__((ext_vector_type(8))) __bf16;
using f32x4  = __attribute__((ext_vector_type(4))) float;

__device__ __forceinline__ float bf2f(u16 h){ return __uint_as_float(((u32)h) << 16); }
__device__ __forceinline__ u16 f2bf(float f){
    u32 u = __float_as_uint(f);
    u32 r = u + 0x7FFFu + ((u >> 16) & 1u);   // round-to-nearest-even
    return (u16)(r >> 16);
}

// async global->LDS, 16B per lane; LDS dest = wave-uniform base + lane*16.
__device__ __forceinline__ void async16(const void* g, void* l){
    __builtin_amdgcn_global_load_lds(
        (const __attribute__((address_space(1))) unsigned int*)g,
        (__attribute__((address_space(3))) unsigned int*)l, 16, 0, 0);
}
__device__ __forceinline__ bf16x8 cvt8(uint4 v){
    union { uint4 u; bf16x8 b; } c; c.u = v; return c.b;
}

// ---------------------------------------------------------------------------
// Block 0: dtype probe. flags[0]=1 if floats bf16; flags[1]=mask dtype
// 0=u8,1=i32,2=bf16,3=f32.
// Block 1: label grouping: slot_of_node[n] = label*128+rank (<128) else
// 384+ovf_rank; node_of_slot inverse (-1 = empty); ovf_flag = #overflow.
// ---------------------------------------------------------------------------
__global__ void probe_and_perm(const void* x, const void* masks, int* flags,
                               const int* labels, int* slot_of_node,
                               int* node_of_slot, int* ovf_flag)
{
    if (blockIdx.x == 0){
        int l = threadIdx.x;
        if (l < 64){
            const u16* hx = (const u16*)x;
            int e0 = (hx[l] >> 7) & 0xFF;
            int e1 = (hx[l + 64] >> 7) & 0xFF;
            unsigned long long b0 = __ballot(e0 >= 100 && e0 <= 140);
            unsigned long long b1 = __ballot(e1 >= 100 && e1 <= 140);
            int cnt = __popcll(b0) + __popcll(b1);
            const u32* w  = (const u32*)masks;
            const u16* hm = (const u16*)masks;
            u32 v = w[l];
            unsigned long long i32bad = __ballot(v > 1u);
            unsigned long long f32bad = __ballot(v != 0u && v != 0x3F800000u);
            u16 h0 = hm[l], h1 = hm[l + 64];
            unsigned long long bfbad =
                __ballot((h0 != 0 && h0 != 0x3F80) || (h1 != 0 && h1 != 0x3F80));
            if (l == 0){
                flags[0] = (cnt >= 100) ? 1 : 0;
                int md = 0;
                if (!i32bad) md = 1; else if (!f32bad) md = 3; else if (!bfbad) md = 2;
                flags[1] = md;
            }
        }
        return;
    }
    __shared__ int lab[300];
    __shared__ unsigned char sp[300];
    int t = threadIdx.x;                      // 320 threads
    for (int idx = t; idx < 512; idx += 320) node_of_slot[idx] = -1;
    if (t < 300) lab[t] = labels[t];
    __syncthreads();
    int r = 0;
    if (t < 300){
        int k = lab[t];
        for (int j = 0; j < t; j++) r += (lab[j] == k);
        sp[t] = (r >= 128) ? 1 : 0;
    }
    __syncthreads();
    if (t < 300){
        int slot;
        if (!sp[t]) slot = lab[t] * 128 + r;
        else {
            int so = 0;
            for (int j = 0; j < t; j++) so += sp[j];
            slot = 384 + so;
        }
        slot_of_node[t] = slot;
        node_of_slot[slot] = t;
    }
    if (t == 0){
        int tot = 0;
        for (int j = 0; j < 300; j++) tot += sp[j];
        *ovf_flag = tot;
    }
}

// ---------------------------------------------------------------------------
// One flat-grid prep kernel: feat transpose (x -> [p][c]), B1T (W1 -> [m][c]),
// W2T (W2 -> [k][r][q]), and bias packing. All bf16-convert, zero-pad j >= J.
// ---------------------------------------------------------------------------
__global__ void prep_combo(const void* x,
    const void* w10, const void* w11, const void* w12,
    const void* w20, const void* w21, const void* w22,
    const void* bb10, const void* bb11, const void* bb12,
    const void* bb20, const void* bb21, const void* bb22,
    u16* feat, u16* B1T, u16* W2T, float* b1f, float* b2f, const int* flags)
{
    __shared__ float tile[32][33];
    const int id = blockIdx.x;
    const bool isbf = (flags[0] != 0);
    const int tid = threadIdx.x;
    const int tx = tid & 31, ty = tid >> 5;

    const void* src; u16* d; int I, J, ldd, i0, j0;
    if (id < 10016){
        int fx = id % 1252, fy = id / 1252;
        src = x; d = feat; I = 256; J = 40000; ldd = 256;
        j0 = fx * 32; i0 = fy * 32;
    } else if (id < 10016 + 768){
        int idx = id - 10016;
        int z = idx / 256, r2 = idx % 256;
        src = (z == 0) ? w10 : (z == 1) ? w11 : w12;
        d = B1T + (size_t)z * 1024 * 256;
        I = 256; J = 1024; ldd = 256;
        j0 = (r2 % 32) * 32; i0 = (r2 / 32) * 32;
    } else if (id < 10016 + 768 + 3072){
        int idx = id - 10016 - 768;
        int z = idx / 1024, r2 = idx % 1024;
        src = (z == 0) ? w20 : (z == 1) ? w21 : w22;
        d = W2T + (size_t)z * 1024 * 1024;
        I = 1024; J = 1024; ldd = 1024;
        j0 = (r2 % 32) * 32; i0 = (r2 / 32) * 32;
    } else {
        int idx = (id - 10016 - 768 - 3072) * 256 + tid;
        if (idx < 3072){
            int k = idx >> 10, r2 = idx & 1023;
            const void* p1 = (k == 0) ? bb10 : (k == 1) ? bb11 : bb12;
            const void* p2 = (k == 0) ? bb20 : (k == 1) ? bb21 : bb22;
            b1f[idx] = isbf ? bf2f(((const u16*)p1)[r2]) : ((const float*)p1)[r2];
            b2f[idx] = isbf ? bf2f(((const u16*)p2)[r2]) : ((const float*)p2)[r2];
        }
        return;
    }
    #pragma unroll
    for (int s = 0; s < 32; s += 8){
        int i = i0 + ty + s, j = j0 + tx;
        float v = 0.f;
        if (j < J){
            size_t ix = (size_t)i * J + j;
            v = isbf ? bf2f(((const u16*)src)[ix]) : ((const float*)src)[ix];
        }
        tile[ty + s][tx] = v;
    }
    __syncthreads();
    #pragma unroll
    for (int s = 0; s < 32; s += 8){
        int j = j0 + ty + s, i = i0 + tx;
        d[(size_t)j * ldd + i] = f2bf(tile[tx][ty + s]);
    }
}

// ---------------------------------------------------------------------------
// masks [P][NN] -> mfT[slot][p] bf16 {0,1} (rows permuted), fused popcount.
// ---------------------------------------------------------------------------
__global__ void trans_mask_count(const void* src, u16* dst,
                                 const int* slot_of_node, float* counts,
                                 const int* flags)
{
    constexpr int NN_ = 300, P_ = 40000, LDP = 40064;
    __shared__ u16 tile[128][33];    // [p_in][n_in]
    __shared__ int slt[32];
    const int p0 = blockIdx.x * 128, n0 = blockIdx.y * 32;
    const int tid = threadIdx.x;
    const int md = flags[1];
    if (tid < 32) slt[tid] = (n0 + tid < NN_) ? slot_of_node[n0 + tid] : -1;

    if (md == 0){
        const unsigned char* s8 = (const unsigned char*)src;
        const int tx = tid & 7, ty = tid >> 3;
        #pragma unroll
        for (int rep = 0; rep < 4; rep++){
            const int p = p0 + rep * 32 + ty;
            const int nb = n0 + tx * 4;
            u32 w = 0;
            if (p < P_){
                if (nb + 3 < NN_)
                    w = *(const u32*)(s8 + (size_t)p * NN_ + nb);
                else {
                    for (int b = 0; b < 4; b++)
                        if (nb + b < NN_)
                            w |= (u32)s8[(size_t)p * NN_ + nb + b] << (8 * b);
                }
            }
            #pragma unroll
            for (int b = 0; b < 4; b++)
                tile[rep * 32 + ty][tx * 4 + b] =
                    ((w >> (8 * b)) & 0xFFu) ? (u16)0x3F80 : (u16)0;
        }
    } else {
        #pragma unroll
        for (int it = 0; it < 16; it++){
            const int e = tid + it * 256;
            const int n_in = e & 31, p_in = e >> 5;
            const int p = p0 + p_in, n = n0 + n_in;
            u16 v = 0;
            if (p < P_ && n < NN_){
                size_t idx = (size_t)p * NN_ + n;
                bool on;
                if (md == 1)      on = ((const int*)src)[idx] != 0;
                else if (md == 2) on = ((const u16*)src)[idx] != 0;
                else              on = ((const float*)src)[idx] != 0.f;
                v = on ? (u16)0x3F80 : (u16)0;
            }
            tile[p_in][n_in] = v;
        }
    }
    __syncthreads();

    #pragma unroll
    for (int half = 0; half < 2; half++){
        const int row = tid >> 3;
        const int pos = (tid & 7) + half * 8;
        const int slot = slt[row];
        if (slot >= 0){
            union { u16 h[8]; uint4 v; } tmp;
            #pragma unroll
            for (int j = 0; j < 8; j++) tmp.h[j] = tile[pos * 8 + j][row];
            *reinterpret_cast<uint4*>(&dst[(size_t)slot * LDP + p0 + pos * 8]) = tmp.v;
        }
    }
    if (tid < 32){
        const int slot = slt[tid];
        if (slot >= 0){
            int c = 0;
            for (int p = 0; p < 128; p++) c += (tile[p][tid] != 0);
            if (c > 0) atomicAdd(&counts[slot], (float)c);
        }
    }
}

// ---------------------------------------------------------------------------
// FUSED L1 + mask-sum v8: de-duplicated wave tiling -> 96 KB global bytes
// per (block, p-tile) instead of 192 KB.
//  - stage-1: wave w owns pixels [w*32, w*32+32): feat frags DISJOINT per
//    wave (read once per block). A = B1T panel resident in LDS (free reuse).
//    acc1[8 m-tiles][2 n-tiles], bias folded into acc1 init. NO barriers.
//  - Hs (16 KB) holds 2 pixel-chunks; written in two wave-parity rounds.
//  - stage-2: wave w owns slots [w*32, w*32+32): mask frags DISJOINT per
//    wave (read once per block). B = H^T from LDS. acc2[2 slot][8 m].
//  - 4 barriers/p-tile. LDS 80 KB -> 2 blocks/CU. ~210 VGPR, no spill.
// MAP 0: grouped slots, sums=[3*128][1024], R6 branch-per-XCD swizzle.
// MAP 1: overflow slots, sums=[128][3072]; early-out when no overflow.
// ---------------------------------------------------------------------------
template<int MAP>
__global__ __launch_bounds__(256, 2)
void fused_l1_mask(const u16* __restrict__ B1T, const u16* __restrict__ feat,
                   const u16* __restrict__ mfT, const float* __restrict__ b1f,
                   float* __restrict__ sums, const int* __restrict__ skipf)
{
    if constexpr (MAP == 1){ if (*skipf == 0) return; }
    constexpr int PPAD = 40064;
    __shared__ __align__(16) u16 As[32768];   // [kt][128 m][32 c]  64 KB
    __shared__ __align__(16) u16 Hs[8192];    // [2 pc][128 m][32 p] 16 KB

    int bx, ts, te;
    if constexpr (MAP == 0){
        // R6 mapping: id = 64g + 8s + r; combo = 8g + r = branch*21 + y;
        // the 8 m-subtiles of a (branch, y) share id%8 -> one XCD.
        const int id = blockIdx.x;
        const int r = id & 7, s = (id >> 3) & 7, g = id >> 6;
        const int combo = g * 8 + r;
        if (combo >= 63) return;
        const int branch = combo / 21, y = combo % 21;
        bx = branch * 8 + s;
        ts = y * 15; te = ts + 15; if (te > 313) te = 313;
    } else {
        bx = blockIdx.x;
        ts = blockIdx.y * 40; te = ts + 40; if (te > 313) te = 313;
        if (ts >= te) return;
    }
    const int m0 = bx * 128;
    const int srow = (MAP == 0) ? ((bx >> 3) * 128) : 384;

    const int tid = threadIdx.x;
    const int wave = tid >> 6, lane = tid & 63;
    const int t = lane & 15, q = lane >> 4;

    // stage B1T panel into As once (per wave, 2 chunks of 16 rows x 64B per kt)
    const int cr = lane >> 2, cp = lane & 3;
    const int ca = wave * 2, cb = wave * 2 + 1;
    {
        const u16* gA0 = B1T + (size_t)(m0 + ca * 16 + cr) * 256 + cp * 8;
        const u16* gA1 = B1T + (size_t)(m0 + cb * 16 + cr) * 256 + cp * 8;
        #pragma unroll
        for (int kt = 0; kt < 8; kt++){
            async16(gA0 + kt * 32, &As[kt * 4096 + ca * 512]);
            async16(gA1 + kt * 32, &As[kt * 4096 + cb * 512]);
        }
    }

    // disjoint per-wave global pointers
    const u16* mrow = mfT + (size_t)(srow + wave*32 + t) * PPAD;   // + si*16*PPAD
    const u16* gF   = feat + (size_t)(wave*32 + t) * 256 + q * 8;  // + p*256 (+ni*16*256)
    const float4* bsrc = reinterpret_cast<const float4*>(b1f + m0) + q;  // + mi*4

    f32x4 acc2[2][8];
    #pragma unroll
    for (int a = 0; a < 2; a++)
        #pragma unroll
        for (int b = 0; b < 8; b++)
            #pragma unroll
            for (int e = 0; e < 4; e++) acc2[a][b][e] = 0.f;

    // prefetch feat frags for (ts, kt=0)
    uint4 bgv[2];
    #pragma unroll
    for (int ni = 0; ni < 2; ni++)
        bgv[ni] = *reinterpret_cast<const uint4*>(
            gF + (size_t)(ts * 128 + ni * 16) * 256);

    __syncthreads();   // As resident (+ bgv drained)

    for (int pt = ts; pt < te; ++pt){
        const int p0 = pt * 128;

        // acc1 init = bias (b1f is 12 KB, L1-resident -> cheap per-pt reload)
        f32x4 acc1[8][2];
        #pragma unroll
        for (int mi = 0; mi < 8; mi++){
            float4 bb = bsrc[mi * 4];
            #pragma unroll
            for (int ni = 0; ni < 2; ni++){
                acc1[mi][ni][0] = bb.x; acc1[mi][ni][1] = bb.y;
                acc1[mi][ni][2] = bb.z; acc1[mi][ni][3] = bb.w;
            }
        }

        uint4 ma0[2], ma1[2], mb0[2], mb1[2];   // mask frags pc 0..3, si 0..1

        // ---- stage-1 K-loop: NO barriers, disjoint feat per wave ----
        #pragma unroll
        for (int kt = 0; kt < 8; ++kt){
            bf16x8 af[8];
            #pragma unroll
            for (int mi = 0; mi < 8; mi++)
                af[mi] = *reinterpret_cast<const bf16x8*>(
                    &As[kt*4096 + (mi*16 + t)*32 + q*8]);
            uint4 nxt[2];
            if (kt < 7){
                #pragma unroll
                for (int ni = 0; ni < 2; ni++)
                    nxt[ni] = *reinterpret_cast<const uint4*>(
                        gF + (size_t)(p0 + ni*16) * 256 + (kt + 1) * 32);
            } else {
                #pragma unroll
                for (int si = 0; si < 2; si++){
                    ma0[si] = *reinterpret_cast<const uint4*>(
                        mrow + (size_t)(si*16)*PPAD + p0 + 0*32 + q*8);
                    ma1[si] = *reinterpret_cast<const uint4*>(
                        mrow + (size_t)(si*16)*PPAD + p0 + 1*32 + q*8);
                }
            }
            #pragma unroll
            for (int mi = 0; mi < 8; mi++)
                #pragma unroll
                for (int ni = 0; ni < 2; ni++)
                    acc1[mi][ni] = __builtin_amdgcn_mfma_f32_16x16x32_bf16(
                        af[mi], cvt8(bgv[ni]), acc1[mi][ni], 0, 0, 0);
            if (kt < 7){
                #pragma unroll
                for (int ni = 0; ni < 2; ni++) bgv[ni] = nxt[ni];
            }
        }

        // ---- round A: waves 0,1 write their pixel-chunk (pc = wave) ----
        if (wave < 2){
            #pragma unroll
            for (int mi = 0; mi < 8; mi++){
                #pragma unroll
                for (int i = 0; i < 4; i++){
                    const int m_l = mi*16 + q*4 + i;
                    #pragma unroll
                    for (int ni = 0; ni < 2; ni++){
                        const int pin = ni*16 + t;
                        float v = acc1[mi][ni][i];
                        v = (v > 0.f) ? v : 0.f;
                        const int cg = (pin >> 3) ^ q;
                        Hs[wave*4096 + m_l*32 + cg*8 + (pin & 7)] = f2bf(v);
                    }
                }
            }
        }
        // prefetch pc 2,3 mask frags (used after next barrier)
        #pragma unroll
        for (int si = 0; si < 2; si++){
            mb0[si] = *reinterpret_cast<const uint4*>(
                mrow + (size_t)(si*16)*PPAD + p0 + 2*32 + q*8);
            mb1[si] = *reinterpret_cast<const uint4*>(
                mrow + (size_t)(si*16)*PPAD + p0 + 3*32 + q*8);
        }
        __syncthreads();

        // ---- stage-2 on pc 0,1: disjoint slots per wave ----
        #pragma unroll
        for (int lc = 0; lc < 2; lc++){
            const uint4* mm = (lc == 0) ? ma0 : ma1;
            bf16x8 hb[8];
            #pragma unroll
            for (int ni = 0; ni < 8; ni++)
                hb[ni] = *reinterpret_cast<const bf16x8*>(
                    &Hs[lc*4096 + (ni*16 + t)*32 + ((q ^ ((t >> 2) & 3)) * 8)]);
            #pragma unroll
            for (int si = 0; si < 2; si++)
                #pragma unroll
                for (int ni = 0; ni < 8; ni++)
                    acc2[si][ni] = __builtin_amdgcn_mfma_f32_16x16x32_bf16(
                        cvt8(mm[si]), hb[ni], acc2[si][ni], 0, 0, 0);
        }
        __syncthreads();

        // ---- round B: waves 2,3 write their pixel-chunk (pc = wave - 2) ----
        if (wave >= 2){
            #pragma unroll
            for (int mi = 0; mi < 8; mi++){
                #pragma unroll
                for (int i = 0; i < 4; i++){
                    const int m_l = mi*16 + q*4 + i;
                    #pragma unroll
                    for (int ni = 0; ni < 2; ni++){
                        const int pin = ni*16 + t;
                        float v = acc1[mi][ni][i];
                        v = (v > 0.f) ? v : 0.f;
                        const int cg = (pin >> 3) ^ q;
                        Hs[(wave-2)*4096 + m_l*32 + cg*8 + (pin & 7)] = f2bf(v);
                    }
                }
            }
        }
        // prefetch next p-tile feat kt=0
        if (pt + 1 < te){
            #pragma unroll
            for (int ni = 0; ni < 2; ni++)
                bgv[ni] = *reinterpret_cast<const uint4*>(
                    gF + (size_t)((pt + 1) * 128 + ni * 16) * 256);
        }
        __syncthreads();

        // ---- stage-2 on pc 2,3 ----
        #pragma unroll
        for (int lc = 0; lc < 2; lc++){
            const uint4* mm = (lc == 0) ? mb0 : mb1;
            bf16x8 hb[8];
            #pragma unroll
            for (int ni = 0; ni < 8; ni++)
                hb[ni] = *reinterpret_cast<const bf16x8*>(
                    &Hs[lc*4096 + (ni*16 + t)*32 + ((q ^ ((t >> 2) & 3)) * 8)]);
            #pragma unroll
            for (int si = 0; si < 2; si++)
                #pragma unroll
                for (int ni = 0; ni < 8; ni++)
                    acc2[si][ni] = __builtin_amdgcn_mfma_f32_16x16x32_bf16(
                        cvt8(mm[si]), hb[ni], acc2[si][ni], 0, 0, 0);
        }
        __syncthreads();   // protect Hs before next p-tile's writes
    }

    // dump accumulators (rows = slots, cols = m)
    #pragma unroll
    for (int si = 0; si < 2; si++){
        #pragma unroll
        for (int i = 0; i < 4; i++){
            const int slot_l = wave*32 + si*16 + q*4 + i;
            #pragma unroll
            for (int ni = 0; ni < 8; ni++){
                const int m_l = ni*16 + t;
                const float v = acc2[si][ni][i];
                if constexpr (MAP == 0)
                    atomicAdd(sums + (size_t)((bx>>3)*128 + slot_l)*1024
                                   + (bx&7)*128 + m_l, v);
                else
                    atomicAdd(sums + (size_t)slot_l*3072 + bx*128 + m_l, v);
            }
        }
    }
}

// ---------------------------------------------------------------------------
// L2 GEMM, fully fused: A = sums (fp32) scaled by 1/count and converted to
// bf16 during LDS staging; B = W2T; epilogue adds bias and scatters straight
// to d_out via node_of_slot. blockIdx.z: 0..2 normal, 3..5 overflow (gated).
// ---------------------------------------------------------------------------
__global__ __launch_bounds__(256)
void l2_gemm(const float* __restrict__ sums3, const float* __restrict__ sumsOvf,
             const float* __restrict__ counts, const u16* __restrict__ W2T,
             const float* __restrict__ b2f, const int* __restrict__ node_of_slot,
             const int* __restrict__ labels, const int* __restrict__ ovfflag,
             void* __restrict__ dout, const int* __restrict__ flags)
{
    const int z = blockIdx.z;
    const int k = (z >= 3) ? z - 3 : z;
    if (z >= 3 && *ovfflag == 0) return;
    const int n0 = blockIdx.x * 128;

    const float* Arow; int astride, slotbase;
    if (z < 3){ Arow = sums3 + (size_t)z * 128 * 1024; astride = 1024; slotbase = z * 128; }
    else      { Arow = sumsOvf + (size_t)k * 1024;     astride = 3072; slotbase = 384; }

    __shared__ __align__(16) u16 As[4096];
    __shared__ __align__(16) u16 Bs[4096];
    __shared__ float invc[128];

    const int tid  = threadIdx.x;
    const int wave = tid >> 6, lane = tid & 63;
    const int wr = wave >> 1, wc = wave & 1;
    const int t = lane & 15, q = lane >> 4;

    if (tid < 128){
        float c = counts[slotbase + tid];
        invc[tid] = (c > 0.f) ? 1.f / c : 0.f;
    }

    const u16* Bsrc = W2T + (size_t)k * 1024 * 1024;
    const int cr = lane >> 2, cp = lane & 3;
    const int ca = wave * 2, cb = wave * 2 + 1;
    const u16* gB0 = Bsrc + (size_t)(n0 + ca * 16 + cr) * 1024 + cp * 8;
    const u16* gB1 = Bsrc + (size_t)(n0 + cb * 16 + cr) * 1024 + cp * 8;

    f32x4 acc[4][4];
    #pragma unroll
    for (int a = 0; a < 4; a++)
        #pragma unroll
        for (int b = 0; b < 4; b++)
            #pragma unroll
            for (int e = 0; e < 4; e++) acc[a][b][e] = 0.f;

    for (int kt = 0; kt < 32; ++kt){
        __syncthreads();
        #pragma unroll
        for (int rep = 0; rep < 2; rep++){
            int idx = tid + rep * 256;
            int row = idx >> 2, quarter = idx & 3;
            const float4* src = reinterpret_cast<const float4*>(
                Arow + (size_t)row * astride + kt * 32 + quarter * 8);
            float4 v0 = src[0], v1 = src[1];
            float s = invc[row];
            union { u16 h[8]; uint4 v; } pk;
            pk.h[0] = f2bf(v0.x * s); pk.h[1] = f2bf(v0.y * s);
            pk.h[2] = f2bf(v0.z * s); pk.h[3] = f2bf(v0.w * s);
            pk.h[4] = f2bf(v1.x * s); pk.h[5] = f2bf(v1.y * s);
            pk.h[6] = f2bf(v1.z * s); pk.h[7] = f2bf(v1.w * s);
            *reinterpret_cast<uint4*>(&As[row * 32 + quarter * 8]) = pk.v;
        }
        async16(gB0 + kt * 32, Bs + ca * 512);
        async16(gB1 + kt * 32, Bs + cb * 512);
        __syncthreads();
        bf16x8 af[4], bg[4];
        #pragma unroll
        for (int mi = 0; mi < 4; mi++)
            af[mi] = *reinterpret_cast<const bf16x8*>(
                &As[(wr*64 + mi*16 + t)*32 + q*8]);
        #pragma unroll
        for (int ni = 0; ni < 4; ni++)
            bg[ni] = *reinterpret_cast<const bf16x8*>(
                &Bs[(wc*64 + ni*16 + t)*32 + q*8]);
        #pragma unroll
        for (int mi = 0; mi < 4; mi++)
            #pragma unroll
            for (int ni = 0; ni < 4; ni++)
                acc[mi][ni] = __builtin_amdgcn_mfma_f32_16x16x32_bf16(
                    af[mi], bg[ni], acc[mi][ni], 0, 0, 0);
    }

    const bool outbf = (flags[0] != 0);
    #pragma unroll
    for (int mi = 0; mi < 4; mi++){
        #pragma unroll
        for (int i = 0; i < 4; i++){
            int m_l = wr*64 + mi*16 + q*4 + i;
            int node = node_of_slot[slotbase + m_l];
            bool ok = (node >= 0) && (z < 3 || labels[node] == k);
            if (!ok) continue;
            #pragma unroll
            for (int ni = 0; ni < 4; ni++){
                int n = n0 + wc*64 + ni*16 + t;
                float v = acc[mi][ni][i] + b2f[k * 1024 + n];
                size_t oi = (size_t)node * 1024 + n;
                if (outbf) ((u16*)dout)[oi] = f2bf(v);
                else       ((float*)dout)[oi] = v;
            }
        }
    }
}

// ---------------------------------------------------------------------------
extern "C" void kernel_launch(void* const* d_in, const int* in_sizes, int n_in,
                              void* d_out, int out_size, void* d_ws, size_t ws_size,
                              hipStream_t stream)
{
    constexpr int C = 256, R = 1024;
    constexpr int PPAD = 40064;          // 313 * 128
    constexpr int M1 = 3 * R;            // 3072 L1 rows (branch-major)
    constexpr int SLOTS = 512;           // 3*128 grouped + 128 overflow

    const void* x      = d_in[0];
    const void* masks  = d_in[1];
    const int*  labels = (const int*)d_in[2];
    (void)in_sizes; (void)n_in; (void)out_size; (void)ws_size;

    char* ws = (char*)d_ws;
    size_t off = 0;
    auto alloc = [&](size_t b)->size_t {
        size_t o = off; off += (b + 255) & ~(size_t)255; return o;
    };

    int*   flags   = (int*)  (ws + alloc(256));
    int*   slotmap = (int*)  (ws + alloc(384 * 4));
    int*   nodemap = (int*)  (ws + alloc(512 * 4));
    int*   ovfflag = (int*)  (ws + alloc(256));
    u16*   feat    = (u16*)  (ws + alloc((size_t)PPAD * C * 2));    // [p][c]
    u16*   B1T     = (u16*)  (ws + alloc((size_t)M1 * C * 2));      // [m][c]
    float* b1f     = (float*)(ws + alloc((size_t)M1 * 4));
    float* b2f     = (float*)(ws + alloc((size_t)M1 * 4));
    u16*   mfT     = (u16*)  (ws + alloc((size_t)SLOTS * PPAD * 2));// [slot][p]
    // contiguous zero region: sums3 | sumsOvf | counts
    float* sums3   = (float*)(ws + alloc((size_t)384 * 1024 * 4));
    float* sumsOvf = (float*)(ws + alloc((size_t)128 * M1 * 4));
    float* counts  = (float*)(ws + alloc((size_t)SLOTS * 4));
    u16*   W2T     = (u16*)  (ws + alloc((size_t)3 * R * R * 2));

    probe_and_perm<<<2, 320, 0, stream>>>(x, masks, flags, labels,
                                          slotmap, nodemap, ovfflag);
    hipMemsetAsync(mfT, 0, (size_t)SLOTS * PPAD * 2, stream);
    hipMemsetAsync(sums3, 0,
        (size_t)384 * 1024 * 4 + (size_t)128 * M1 * 4 + (size_t)SLOTS * 4, stream);

    prep_combo<<<10016 + 768 + 3072 + 12, 256, 0, stream>>>(
        x, d_in[3], d_in[7], d_in[11],           // W1
        d_in[5], d_in[9], d_in[13],              // W2
        d_in[4], d_in[8], d_in[12],              // b1
        d_in[6], d_in[10], d_in[14],             // b2
        feat, B1T, W2T, b1f, b2f, flags);

    trans_mask_count<<<dim3(PPAD / 128, 384 / 32), 256, 0, stream>>>(
        masks, mfT, slotmap, counts, flags);

    // fused L1 + mask-sum: 512 ids (8 idle), branch-per-XCD swizzle
    fused_l1_mask<0><<<512, 256, 0, stream>>>(
        B1T, feat, mfT, b1f, sums3, nullptr);
    // overflow path (skipped unless some label has > 128 nodes)
    fused_l1_mask<1><<<dim3(24, 8), 256, 0, stream>>>(
        B1T, feat, mfT, b1f, sumsOvf, ovfflag);

    // L2 + means + output gather, one launch
    l2_gemm<<<dim3(8, 1, 6), 256, 0, stream>>>(
        sums3, sumsOvf, counts, W2T, b2f, nodemap, labels, ovfflag,
        d_out, flags);
}